// Round 2
// baseline (385.396 us; speedup 1.0000x reference)
//
#include <hip/hip_runtime.h>
#include <math.h>

#define BATCH 4
#define HEADS 16
#define SEQ   4096
#define DIM   64
#define BHN   (BATCH*HEADS)   // 64
#define NS1   16              // pass-1 S-chunks per (b,h)
#define ROWS1 (SEQ/NS1)       // 256 rows per pass1 block
#define P2_RPB 128            // pass-2 rows per block (4 waves x 32)
#define NB2   (SEQ/P2_RPB)    // 32 blocks per bh

// workspace layout (float offsets)
#define WS_TAB   0                                   // S*32      = 131072
#define WS_MPART (WS_TAB   + SEQ*32)                 // NS1*BH*4096
#define WS_KPART (WS_MPART + NS1*BHN*DIM*DIM)
#define WS_MFIN  (WS_KPART + NS1*BHN*DIM)
#define WS_KFIN  (WS_MFIN  + BHN*DIM*DIM)

// ---------------------------------------------------------------- cos/sin table
__global__ __launch_bounds__(256) void k_table(float* __restrict__ tab) {
    int g = blockIdx.x * 256 + threadIdx.x;      // 0 .. S*16-1
    int s = g >> 4;
    int i = g & 15;
    double inv = exp(-(double)i * (9.210340371976184 / 16.0));  // 10000^(-i/16)
    float af = (float)((double)s * inv);
    float sn, cs;
    sincosf(af, &sn, &cs);
    tab[2*g]   = cs;
    tab[2*g+1] = sn;
}

// ---------------------------------------------------------------- pass 1: M = Kr^T V (blocked layout), ksum
// Each wave owns the full 64x64 M in an 8x8 register tile; rows split across waves.
// M stored in blocked "scrambled" layout: elem(d,e) at p = ((d>>3)*8+(e>>3))*64 + (d&7)*8 + (e&7)
__global__ __launch_bounds__(256) void k_pass1(const float* __restrict__ K,
                                               const float* __restrict__ V,
                                               const int*   __restrict__ mask,
                                               const float* __restrict__ tab,
                                               float* __restrict__ Mpart,
                                               float* __restrict__ Kpart) {
    __shared__ float Kr[64*68];       // 17408 B; also aliased as redA (needs 64*65=4160 floats)
    __shared__ float redB[64*65];     // 16640 B
    __shared__ float ksred[8*64];     // 2048 B
    float* redA = Kr;

    const int t    = threadIdx.x;
    const int w    = t >> 6;          // wave 0..3
    const int lane = t & 63;
    const int bh   = blockIdx.x >> 4;
    const int ns   = blockIdx.x & 15;
    const int b    = bh >> 4;         // H = 16
    const int s0blk = ns * ROWS1;
    const size_t base = (size_t)bh * SEQ;

    const int dp = t & 31;            // staging: column pair 0..31
    const int ro = t >> 5;            // staging: 0..7
    const int gi = lane >> 3;         // gemm: M-row group 0..7
    const int gj = lane & 7;          // gemm: M-col group 0..7

    float acc[8][8];
    #pragma unroll
    for (int i = 0; i < 8; ++i)
        #pragma unroll
        for (int j = 0; j < 8; ++j) acc[i][j] = 0.f;
    float ks0 = 0.f, ks1 = 0.f;

    for (int tile = 0; tile < ROWS1/64; ++tile) {
        const int s0 = s0blk + tile*64;
        // ---- stage Kr: K -> elu+1 -> mask -> (ksum) -> rope -> LDS
        #pragma unroll
        for (int it = 0; it < 8; ++it) {
            const int sl   = it*8 + ro;
            const int srow = s0 + sl;
            float2 kv = *(const float2*)(K + (base + srow)*DIM + dp*2);
            float fm = (float)mask[b*SEQ + srow];
            float k0 = kv.x > 0.f ? kv.x + 1.f : __expf(kv.x);
            float k1 = kv.y > 0.f ? kv.y + 1.f : __expf(kv.y);
            k0 *= fm; k1 *= fm;
            ks0 += fabsf(k0); ks1 += fabsf(k1);
            float r0 = k0, r1 = k1;
            if (dp < 16) {
                float2 cs = *(const float2*)(tab + (size_t)srow*32 + dp*2);
                r0 = k0*cs.x - k1*cs.y;
                r1 = k1*cs.x + k0*cs.y;
            }
            *(float2*)&Kr[sl*68 + dp*2] = make_float2(r0, r1);
        }
        __syncthreads();
        // ---- gemm: wave w handles rows w*16 .. w*16+15 of this tile
        const float* vlane = V + (base + s0 + w*16)*DIM + gj*8;
        #pragma unroll 2
        for (int sr = 0; sr < 16; ++sr) {
            const int sl = w*16 + sr;
            float4 ka0 = *(const float4*)&Kr[sl*68 + gi*8];
            float4 ka1 = *(const float4*)&Kr[sl*68 + gi*8 + 4];
            float4 vb0 = *(const float4*)(vlane + sr*DIM);
            float4 vb1 = *(const float4*)(vlane + sr*DIM + 4);
            float a[8]  = {ka0.x, ka0.y, ka0.z, ka0.w, ka1.x, ka1.y, ka1.z, ka1.w};
            float bb[8] = {vb0.x, vb0.y, vb0.z, vb0.w, vb1.x, vb1.y, vb1.z, vb1.w};
            #pragma unroll
            for (int i = 0; i < 8; ++i)
                #pragma unroll
                for (int j = 0; j < 8; ++j)
                    acc[i][j] += a[i] * bb[j];
        }
        __syncthreads();
    }

    // ---- ksum partials to LDS
    ksred[ro*64 + 2*dp]     = ks0;
    ksred[ro*64 + 2*dp + 1] = ks1;

    // ---- cross-wave reduce of acc (conflict-free: lane-column layout, stride 65)
    if (w == 0) {
        #pragma unroll
        for (int i = 0; i < 8; ++i)
            #pragma unroll
            for (int j = 0; j < 8; ++j) redA[lane*65 + i*8 + j] = acc[i][j];
    } else if (w == 1) {
        #pragma unroll
        for (int i = 0; i < 8; ++i)
            #pragma unroll
            for (int j = 0; j < 8; ++j) redB[lane*65 + i*8 + j] = acc[i][j];
    }
    __syncthreads();
    if (w == 2) {
        #pragma unroll
        for (int i = 0; i < 8; ++i)
            #pragma unroll
            for (int j = 0; j < 8; ++j) redA[lane*65 + i*8 + j] += acc[i][j];
    } else if (w == 3) {
        #pragma unroll
        for (int i = 0; i < 8; ++i)
            #pragma unroll
            for (int j = 0; j < 8; ++j) redB[lane*65 + i*8 + j] += acc[i][j];
    } else if (t < 64) {
        // wave0 is idle here: finish ksum
        float s = 0.f;
        #pragma unroll
        for (int g = 0; g < 8; ++g) s += ksred[g*64 + t];
        Kpart[blockIdx.x*DIM + t] = s;
    }
    __syncthreads();
    // merge redA += redB (each thread 16 elems, conflict-free)
    #pragma unroll
    for (int q = 0; q < 16; ++q) {
        const int idx = lane*65 + w*16 + q;
        redA[idx] += redB[idx];
    }
    __syncthreads();
    // ---- coalesced Mpart write (blocked/scrambled layout preserved)
    float* pm = Mpart + (size_t)blockIdx.x * (DIM*DIM);
    #pragma unroll
    for (int k2 = 0; k2 < 16; ++k2) {
        const int p = t + 256*k2;
        pm[p] = redA[(p >> 6)*65 + (p & 63)];
    }
}

// ---------------------------------------------------------------- reduce partials
__global__ __launch_bounds__(256) void k_reduce(const float* __restrict__ Mpart,
                                                const float* __restrict__ Kpart,
                                                float* __restrict__ Mfin,
                                                float* __restrict__ Kfin) {
    int g = blockIdx.x * 256 + threadIdx.x;
    if (g < BHN*DIM*DIM) {
        int bh = g >> 12, j = g & 4095;
        float s = 0.f;
        #pragma unroll
        for (int ns = 0; ns < NS1; ++ns)
            s += Mpart[(size_t)(bh*NS1 + ns)*(DIM*DIM) + j];
        Mfin[g] = s;
    } else {
        int k = g - BHN*DIM*DIM;
        if (k < BHN*DIM) {
            int bh = k >> 6, d = k & 63;
            float s = 0.f;
            #pragma unroll
            for (int ns = 0; ns < NS1; ++ns)
                s += Kpart[(bh*NS1 + ns)*DIM + d];
            Kfin[k] = s;
        }
    }
}

// ---------------------------------------------------------------- pass 2: out = (Qr M) / (Qf . ksum)
// Wave-private staging (no __syncthreads). M read from global in blocked layout.
__global__ __launch_bounds__(256) void k_pass2(const float* __restrict__ Q,
                                               const float* __restrict__ tab,
                                               const float* __restrict__ Mfin,
                                               const float* __restrict__ ksum,
                                               float* __restrict__ out) {
    __shared__ float Qr[4][32*68];    // per-wave 32-row tiles (8704 B each)
    __shared__ float nrm[4][32];

    const int t    = threadIdx.x;
    const int w    = t >> 6;
    const int lane = t & 63;
    const int bh   = blockIdx.x >> 5;     // / NB2
    const int blk  = blockIdx.x & 31;
    const int rowbase = blk*P2_RPB + w*32;
    const size_t base = (size_t)bh * SEQ;

    const int c4 = lane & 15;             // float4 column 0..15
    const int ro = lane >> 4;             // 0..3

    const float4 ks = *(const float4*)(ksum + bh*DIM + c4*4);
    float* qw = &Qr[w][0];

    // ---- stage 32 rows: Q -> elu(q/8)+1 -> norm(shfl) -> rope -> LDS (row-major)
    #pragma unroll
    for (int p = 0; p < 8; ++p) {
        const int r    = p*4 + ro;
        const int srow = rowbase + r;
        float4 qv = *(const float4*)(Q + (base + srow)*DIM + c4*4);
        float x0 = qv.x*0.125f, x1 = qv.y*0.125f, x2 = qv.z*0.125f, x3 = qv.w*0.125f;
        float q0 = x0 > 0.f ? x0 + 1.f : __expf(x0);
        float q1 = x1 > 0.f ? x1 + 1.f : __expf(x1);
        float q2 = x2 > 0.f ? x2 + 1.f : __expf(x2);
        float q3 = x3 > 0.f ? x3 + 1.f : __expf(x3);
        float np = q0*ks.x + q1*ks.y + q2*ks.z + q3*ks.w;
        np += __shfl_xor(np, 1);
        np += __shfl_xor(np, 2);
        np += __shfl_xor(np, 4);
        np += __shfl_xor(np, 8);
        if (c4 == 0) nrm[w][r] = np;
        float r0, r1, r2, r3;
        if (c4 < 8) {
            float4 cs = *(const float4*)(tab + (size_t)srow*32 + c4*4);
            r0 = q0*cs.x - q1*cs.y;
            r1 = q1*cs.x + q0*cs.y;
            r2 = q2*cs.z - q3*cs.w;
            r3 = q3*cs.z + q2*cs.w;
        } else {
            r0 = q0; r1 = q1; r2 = q2; r3 = q3;
        }
        *(float4*)&qw[r*68 + c4*4] = make_float4(r0, r1, r2, r3);
    }
    // same-wave LDS write->read dependency: compiler inserts lgkmcnt wait.

    const int rgp = lane >> 3;            // 0..7 (row within stride-8 groups)
    const int cg  = lane & 7;             // 0..7 (8-col group)
    const float* mrow = Mfin + bh*(DIM*DIM);

    float acc[4][8];
    #pragma unroll
    for (int i = 0; i < 4; ++i)
        #pragma unroll
        for (int j = 0; j < 8; ++j) acc[i][j] = 0.f;

    #pragma unroll 2
    for (int d0 = 0; d0 < 64; d0 += 4) {
        float qAr[4][4];
        #pragma unroll
        for (int i = 0; i < 4; ++i) {
            float4 qa = *(const float4*)&qw[(rgp + 8*i)*68 + d0];
            qAr[i][0] = qa.x; qAr[i][1] = qa.y; qAr[i][2] = qa.z; qAr[i][3] = qa.w;
        }
        #pragma unroll
        for (int k = 0; k < 4; ++k) {
            const int d = d0 + k;
            const float* mp = mrow + ((d >> 3)*512 + cg*64 + (d & 7)*8);
            float4 m0 = *(const float4*)mp;
            float4 m1 = *(const float4*)(mp + 4);
            float mm[8] = {m0.x, m0.y, m0.z, m0.w, m1.x, m1.y, m1.z, m1.w};
            #pragma unroll
            for (int i = 0; i < 4; ++i)
                #pragma unroll
                for (int j = 0; j < 8; ++j)
                    acc[i][j] += qAr[i][k] * mm[j];
        }
    }

    // ---- epilogue: divide by norm, store
    #pragma unroll
    for (int i = 0; i < 4; ++i) {
        const int r = rgp + 8*i;
        const float inv = 1.0f / nrm[w][r];
        float4 o0 = make_float4(acc[i][0]*inv, acc[i][1]*inv, acc[i][2]*inv, acc[i][3]*inv);
        float4 o1 = make_float4(acc[i][4]*inv, acc[i][5]*inv, acc[i][6]*inv, acc[i][7]*inv);
        float* op = out + (base + rowbase + r)*DIM + cg*8;
        *(float4*)op       = o0;
        *(float4*)(op + 4) = o1;
    }
}

// ---------------------------------------------------------------- launch
extern "C" void kernel_launch(void* const* d_in, const int* in_sizes, int n_in,
                              void* d_out, int out_size, void* d_ws, size_t ws_size,
                              hipStream_t stream) {
    const float* Q    = (const float*)d_in[0];
    const float* K    = (const float*)d_in[1];
    const float* V    = (const float*)d_in[2];
    const int*   mask = (const int*)d_in[3];
    float* out = (float*)d_out;
    float* ws  = (float*)d_ws;

    float* tab   = ws + WS_TAB;
    float* Mpart = ws + WS_MPART;
    float* Kpart = ws + WS_KPART;
    float* Mfin  = ws + WS_MFIN;
    float* Kfin  = ws + WS_KFIN;

    k_table <<<SEQ*16/256, 256, 0, stream>>>(tab);
    k_pass1 <<<BHN*NS1,    256, 0, stream>>>(K, V, mask, tab, Mpart, Kpart);
    k_reduce<<<(BHN*DIM*DIM + BHN*DIM + 255)/256, 256, 0, stream>>>(Mpart, Kpart, Mfin, Kfin);
    k_pass2 <<<BHN*NB2,    256, 0, stream>>>(Q, tab, Mfin, Kfin, out);
}

// Round 3
// 243.596 us; speedup vs baseline: 1.5821x; 1.5821x over previous
//
#include <hip/hip_runtime.h>
#include <math.h>

#define SEQ   4096
#define DIM   64
#define BHN   64              // B*H
#define NS1   16              // pass-1 S-chunks per (b,h)
#define LSTR  72              // ushort stride for LDS tiles (144B: 16B-aligned, non-pow2)

typedef __attribute__((ext_vector_type(8))) __bf16 bf16x8;
typedef __attribute__((ext_vector_type(4))) float  f32x4;
typedef unsigned short u16;
typedef unsigned int   u32;

// workspace layout (float offsets)
#define WS_TAB   0                                   // 131072
#define WS_MPART (WS_TAB   + SEQ*32)                 // + 1024*4096
#define WS_KPART (WS_MPART + NS1*BHN*DIM*DIM)        // + 65536
#define WS_MT    (WS_KPART + NS1*BHN*DIM)            // 262144 ushorts = 131072 floats
#define WS_KFIN  (WS_MT    + BHN*DIM*DIM/2)          // + 4096

__device__ __forceinline__ u16 f2bf(float x) {
    union { float f; u32 u; } v; v.f = x;
    u32 r = v.u + 0x7fffu + ((v.u >> 16) & 1u);
    return (u16)(r >> 16);
}

// ---------------------------------------------------------------- cos/sin table
__global__ __launch_bounds__(256) void k_table(float* __restrict__ tab) {
    int g = blockIdx.x * 256 + threadIdx.x;      // 0 .. S*16-1
    int s = g >> 4;
    int i = g & 15;
    double inv = exp(-(double)i * (9.210340371976184 / 16.0));  // 10000^(-i/16)
    float af = (float)((double)s * inv);
    float sn, cs;
    sincosf(af, &sn, &cs);
    tab[2*g]   = cs;
    tab[2*g+1] = sn;
}

// ---------------------------------------------------------------- pass 1: M = Kr^T V via MFMA, ksum
// KrT/VT staged transposed (bf16): fragment reads become row-contiguous b128.
// A-frag: lane l -> A[l&15][8*(l>>4)..+7]; C/D: col=lane&15, row=4*(lane>>4)+reg (m89).
__global__ __launch_bounds__(256) void k_pass1(const float* __restrict__ K,
                                               const float* __restrict__ V,
                                               const int*   __restrict__ mask,
                                               const float* __restrict__ tab,
                                               float* __restrict__ Mpart,
                                               float* __restrict__ Kpart) {
    __shared__ u16 KrT[64*LSTR];     // [d][s] bf16
    __shared__ u16 VT [64*LSTR];     // [e][s] bf16
    __shared__ float ksred[16*64];

    const int t    = threadIdx.x;
    const int w    = t >> 6;          // wave 0..3
    const int lane = t & 63;
    const int bh   = blockIdx.x >> 4;
    const int ns   = blockIdx.x & 15;
    const int b    = bh >> 4;         // H = 16
    const size_t base = (size_t)bh * SEQ;
    const int s0blk = ns * 256;

    const int cg = t & 15;            // staging: cols 4cg..+3
    const int R  = t >> 4;            // staging: rows 4R+i
    const int ar = lane & 15;         // frag row
    const int ag = lane >> 4;         // frag k-group

    float ks[4] = {0.f, 0.f, 0.f, 0.f};
    f32x4 acc[4];
    #pragma unroll
    for (int n = 0; n < 4; ++n) acc[n] = (f32x4){0.f, 0.f, 0.f, 0.f};

    for (int tile = 0; tile < 4; ++tile) {
        const int s0 = s0blk + tile*64;
        float kk[4][4], vv[4][4];
        #pragma unroll
        for (int i = 0; i < 4; ++i) {
            const int row  = 4*R + i;
            const int srow = s0 + row;
            float4 kq = *(const float4*)(K + (base + srow)*DIM + cg*4);
            float4 vq = *(const float4*)(V + (base + srow)*DIM + cg*4);
            float fm = (float)mask[b*SEQ + srow];
            float k0 = kq.x > 0.f ? kq.x + 1.f : __expf(kq.x);
            float k1 = kq.y > 0.f ? kq.y + 1.f : __expf(kq.y);
            float k2 = kq.z > 0.f ? kq.z + 1.f : __expf(kq.z);
            float k3 = kq.w > 0.f ? kq.w + 1.f : __expf(kq.w);
            k0 *= fm; k1 *= fm; k2 *= fm; k3 *= fm;
            ks[0] += k0; ks[1] += k1; ks[2] += k2; ks[3] += k3;   // Kf >= 0
            float r0 = k0, r1 = k1, r2 = k2, r3 = k3;
            if (cg < 8) {
                float4 cs = *(const float4*)(tab + (size_t)srow*32 + cg*4);
                r0 = k0*cs.x - k1*cs.y;
                r1 = k1*cs.x + k0*cs.y;
                r2 = k2*cs.z - k3*cs.w;
                r3 = k3*cs.z + k2*cs.w;
            }
            kk[i][0]=r0; kk[i][1]=r1; kk[i][2]=r2; kk[i][3]=r3;
            vv[i][0]=vq.x; vv[i][1]=vq.y; vv[i][2]=vq.z; vv[i][3]=vq.w;
        }
        // transposed packed writes: col (4cg+j) gets rows 4R..4R+3
        #pragma unroll
        for (int j = 0; j < 4; ++j) {
            ushort4 pk = make_ushort4(f2bf(kk[0][j]), f2bf(kk[1][j]), f2bf(kk[2][j]), f2bf(kk[3][j]));
            ushort4 pv = make_ushort4(f2bf(vv[0][j]), f2bf(vv[1][j]), f2bf(vv[2][j]), f2bf(vv[3][j]));
            *(ushort4*)&KrT[(4*cg + j)*LSTR + 4*R] = pk;
            *(ushort4*)&VT [(4*cg + j)*LSTR + 4*R] = pv;
        }
        __syncthreads();
        // MFMA: wave w owns d-strip 16w..16w+15, 4 e-tiles, K=64 (2 steps)
        #pragma unroll
        for (int kstep = 0; kstep < 2; ++kstep) {
            bf16x8 af = *(const bf16x8*)&KrT[(16*w + ar)*LSTR + 32*kstep + 8*ag];
            #pragma unroll
            for (int n = 0; n < 4; ++n) {
                bf16x8 bf = *(const bf16x8*)&VT[(16*n + ar)*LSTR + 32*kstep + 8*ag];
                acc[n] = __builtin_amdgcn_mfma_f32_16x16x32_bf16(af, bf, acc[n], 0, 0, 0);
            }
        }
        __syncthreads();
    }

    // ksum partial reduce
    #pragma unroll
    for (int j = 0; j < 4; ++j) ksred[R*64 + 4*cg + j] = ks[j];
    __syncthreads();
    if (t < 64) {
        float s = 0.f;
        #pragma unroll
        for (int g = 0; g < 16; ++g) s += ksred[g*64 + t];
        Kpart[blockIdx.x*DIM + t] = s;
    }

    // Mpart write (fp32): d = 16w+4ag+r, e = 16n+ar
    float* pm = Mpart + (size_t)blockIdx.x * (DIM*DIM);
    #pragma unroll
    for (int n = 0; n < 4; ++n)
        #pragma unroll
        for (int r = 0; r < 4; ++r)
            pm[(16*w + 4*ag + r)*DIM + 16*n + ar] = acc[n][r];
}

// ---------------------------------------------------------------- reduce partials -> MT (bf16, transposed), Kfin
__global__ __launch_bounds__(256) void k_reduce(const float* __restrict__ Mpart,
                                                const float* __restrict__ Kpart,
                                                u16*   __restrict__ MT,
                                                float* __restrict__ Kfin) {
    int g = blockIdx.x * 256 + threadIdx.x;
    if (g < BHN*4096) {
        int bh = g >> 12, rem = g & 4095;
        int d = rem >> 6, e = rem & 63;
        float s = 0.f;
        #pragma unroll
        for (int ns = 0; ns < NS1; ++ns)
            s += Mpart[(size_t)(bh*NS1 + ns)*4096 + rem];
        MT[(size_t)bh*4096 + e*64 + d] = f2bf(s);    // store M^T row-major [e][d]
    } else {
        int k = g - BHN*4096;        // 0..4095
        int bh = k >> 6, dd = k & 63;
        float s = 0.f;
        #pragma unroll
        for (int ns = 0; ns < NS1; ++ns)
            s += Kpart[(bh*NS1 + ns)*DIM + dd];
        Kfin[k] = s;
    }
}

// ---------------------------------------------------------------- pass 2: out = (Qr M) / (Qf . ksum) via MFMA
__global__ __launch_bounds__(256) void k_pass2(const float* __restrict__ Q,
                                               const float* __restrict__ tab,
                                               const u16*   __restrict__ MT,
                                               const float* __restrict__ ksum,
                                               float* __restrict__ out) {
    __shared__ u16 MTl[64*LSTR];     // M^T [e][d] bf16
    __shared__ u16 Qr [64*LSTR];     // Qr  [s][d] bf16
    __shared__ float nrm[64];

    const int t    = threadIdx.x;
    const int w    = t >> 6;
    const int lane = t & 63;
    const int bh   = blockIdx.x >> 5;
    const int blk  = blockIdx.x & 31;
    const size_t base = (size_t)bh * SEQ;
    const int rowbase0 = blk * 128;

    const int cg = t & 15;
    const int rg = t >> 4;
    const int ar = lane & 15;
    const int ag = lane >> 4;

    {   // stage M^T once (8 KB)
        const uint4* mg = (const uint4*)(MT + (size_t)bh*4096);
        #pragma unroll
        for (int i = 0; i < 2; ++i) {
            int idx = i*256 + t;
            int row = idx >> 3, c8 = idx & 7;
            *(uint4*)&MTl[row*LSTR + c8*8] = mg[idx];
        }
    }
    const float4 ksq = *(const float4*)(ksum + bh*DIM + cg*4);
    __syncthreads();

    for (int half = 0; half < 2; ++half) {
        const int rowb = rowbase0 + half*64;
        // ---- stage Qr (64 rows): elu(q/8)+1 -> norm (16-lane shfl) -> rope -> bf16 LDS
        #pragma unroll
        for (int i = 0; i < 4; ++i) {
            const int row  = 16*i + rg;
            const int srow = rowb + row;
            float4 qv = *(const float4*)(Q + (base + srow)*DIM + cg*4);
            float x0 = qv.x*0.125f, x1 = qv.y*0.125f, x2 = qv.z*0.125f, x3 = qv.w*0.125f;
            float q0 = x0 > 0.f ? x0 + 1.f : __expf(x0);
            float q1 = x1 > 0.f ? x1 + 1.f : __expf(x1);
            float q2 = x2 > 0.f ? x2 + 1.f : __expf(x2);
            float q3 = x3 > 0.f ? x3 + 1.f : __expf(x3);
            float np = q0*ksq.x + q1*ksq.y + q2*ksq.z + q3*ksq.w;
            np += __shfl_xor(np, 1);
            np += __shfl_xor(np, 2);
            np += __shfl_xor(np, 4);
            np += __shfl_xor(np, 8);
            if (cg == 0) nrm[row] = np;
            float r0 = q0, r1 = q1, r2 = q2, r3 = q3;
            if (cg < 8) {
                float4 cs = *(const float4*)(tab + (size_t)srow*32 + cg*4);
                r0 = q0*cs.x - q1*cs.y;
                r1 = q1*cs.x + q0*cs.y;
                r2 = q2*cs.z - q3*cs.w;
                r3 = q3*cs.z + q2*cs.w;
            }
            *(ushort4*)&Qr[row*LSTR + cg*4] =
                make_ushort4(f2bf(r0), f2bf(r1), f2bf(r2), f2bf(r3));
        }
        __syncthreads();
        // ---- MFMA: wave w owns rows 16w..16w+15, 4 e-tiles
        f32x4 acc[4];
        #pragma unroll
        for (int n = 0; n < 4; ++n) acc[n] = (f32x4){0.f, 0.f, 0.f, 0.f};
        #pragma unroll
        for (int kstep = 0; kstep < 2; ++kstep) {
            bf16x8 af = *(const bf16x8*)&Qr[(16*w + ar)*LSTR + 32*kstep + 8*ag];
            #pragma unroll
            for (int n = 0; n < 4; ++n) {
                bf16x8 bf = *(const bf16x8*)&MTl[(16*n + ar)*LSTR + 32*kstep + 8*ag];
                acc[n] = __builtin_amdgcn_mfma_f32_16x16x32_bf16(af, bf, acc[n], 0, 0, 0);
            }
        }
        // ---- epilogue: /norm, store (row = 16w+4ag+r, e = 16n+ar)
        #pragma unroll
        for (int r = 0; r < 4; ++r) {
            const int row = 16*w + 4*ag + r;
            const float inv = 1.0f / nrm[row];
            #pragma unroll
            for (int n = 0; n < 4; ++n)
                out[(base + rowb + row)*DIM + 16*n + ar] = acc[n][r] * inv;
        }
        __syncthreads();
    }
}

// ---------------------------------------------------------------- launch
extern "C" void kernel_launch(void* const* d_in, const int* in_sizes, int n_in,
                              void* d_out, int out_size, void* d_ws, size_t ws_size,
                              hipStream_t stream) {
    const float* Q    = (const float*)d_in[0];
    const float* K    = (const float*)d_in[1];
    const float* V    = (const float*)d_in[2];
    const int*   mask = (const int*)d_in[3];
    float* out = (float*)d_out;
    float* ws  = (float*)d_ws;

    float* tab   = ws + WS_TAB;
    float* Mpart = ws + WS_MPART;
    float* Kpart = ws + WS_KPART;
    u16*   MT    = (u16*)(ws + WS_MT);
    float* Kfin  = ws + WS_KFIN;

    k_table <<<SEQ*16/256, 256, 0, stream>>>(tab);
    k_pass1 <<<BHN*NS1,    256, 0, stream>>>(K, V, mask, tab, Mpart, Kpart);
    k_reduce<<<1040,       256, 0, stream>>>(Mpart, Kpart, MT, Kfin);
    k_pass2 <<<BHN*32,     256, 0, stream>>>(Q, tab, MT, Kfin, out);
}